// Round 1
// baseline (32481.827 us; speedup 1.0000x reference)
//
#include <hip/hip_runtime.h>

#define NN 500000
#define NE 8000000
#define NG 5000
#define CH 8
#define NCONV 8
#define HID 128
#define BEPS 1e-5f

static inline size_t alignup(size_t v, size_t a) { return (v + a - 1) / a * a; }

// ---------------- init: deg=1 (self loop), zero pooled + stats ----------------
__global__ void k_init(float* __restrict__ deg, float* __restrict__ pooled,
                       double* __restrict__ stats) {
    int i = blockIdx.x * 256 + threadIdx.x;
    if (i < NN) deg[i] = 1.0f;
    if (i < NG * CH) pooled[i] = 0.0f;
    if (i < (NCONV + 1) * 2 * CH) stats[i] = 0.0;
}

// ---------------- degree over dst ----------------
__global__ void k_degree(const int* __restrict__ dst, float* __restrict__ deg) {
    int e = blockIdx.x * 256 + threadIdx.x;
    if (e < NE) atomicAdd(&deg[dst[e]], 1.0f);
}

// per-wave sum/sumsq reduce of v[CH], lane0 -> f64 atomics into slot[0..7]=sum, [8..15]=sumsq
__device__ __forceinline__ void wave_stats_accum(const float v[CH], double* __restrict__ slot) {
#pragma unroll
    for (int c = 0; c < CH; c++) {
        float s = v[c], q = v[c] * v[c];
#pragma unroll
        for (int off = 32; off; off >>= 1) {
            s += __shfl_xor(s, off);
            q += __shfl_xor(q, off);
        }
        if ((threadIdx.x & 63) == 0) {
            atomicAdd(&slot[c], (double)s);
            atomicAdd(&slot[CH + c], (double)q);
        }
    }
}

// ---------------- embed + dinv + stats for conv 0 ----------------
__global__ void k_embed(const int* __restrict__ x, const float* __restrict__ emb,
                        float* __restrict__ h, float* __restrict__ deg_dinv,
                        double* __restrict__ stats0) {
    int i = blockIdx.x * 256 + threadIdx.x;
    float v[CH];
    if (i < NN) {
        deg_dinv[i] = rsqrtf(deg_dinv[i]);
        int t = x[i];
#pragma unroll
        for (int c = 0; c < CH; c++) v[c] = emb[t * CH + c];
        float4* hp = (float4*)(h + (size_t)i * CH);
        hp[0] = make_float4(v[0], v[1], v[2], v[3]);
        hp[1] = make_float4(v[4], v[5], v[6], v[7]);
    } else {
#pragma unroll
        for (int c = 0; c < CH; c++) v[c] = 0.0f;
    }
    wave_stats_accum(v, stats0);
}

// ---------------- BN + 8x8 linear + agg init (residual + bias + self-loop term) ----------------
__global__ void k_transform(const float* __restrict__ h, const float* __restrict__ dinv,
                            const double* __restrict__ stats,
                            const float* __restrict__ gamma, const float* __restrict__ beta,
                            const float* __restrict__ W, const float* __restrict__ bias,
                            float* __restrict__ hw, float* __restrict__ agg) {
    __shared__ float sW[CH * CH], sScale[CH], sShift[CH], sB[CH];
    int tid = threadIdx.x;
    if (tid < CH * CH) sW[tid] = W[tid];
    if (tid < CH) {
        double mu = stats[tid] * (1.0 / NN);
        double var = stats[CH + tid] * (1.0 / NN) - mu * mu;
        float sc = gamma[tid] * rsqrtf((float)var + BEPS);
        sScale[tid] = sc;
        sShift[tid] = beta[tid] - (float)mu * sc;
        sB[tid] = bias[tid];
    }
    __syncthreads();
    int i = blockIdx.x * 256 + tid;
    if (i >= NN) return;
    const float4* hp = (const float4*)(h + (size_t)i * CH);
    float4 h0 = hp[0], h1 = hp[1];
    float hv[CH] = {h0.x, h0.y, h0.z, h0.w, h1.x, h1.y, h1.z, h1.w};
    float hb[CH];
#pragma unroll
    for (int c = 0; c < CH; c++) hb[c] = hv[c] * sScale[c] + sShift[c];
    float o[CH];
#pragma unroll
    for (int j = 0; j < CH; j++) {
        float a = 0.0f;
#pragma unroll
        for (int c = 0; c < CH; c++) a += hb[c] * sW[c * CH + j];
        o[j] = a;
    }
    float d = dinv[i];
    float d2 = d * d;
    float4* hwp = (float4*)(hw + (size_t)i * CH);
    hwp[0] = make_float4(o[0], o[1], o[2], o[3]);
    hwp[1] = make_float4(o[4], o[5], o[6], o[7]);
    float4* ap = (float4*)(agg + (size_t)i * CH);
    ap[0] = make_float4(hv[0] + sB[0] + o[0] * d2, hv[1] + sB[1] + o[1] * d2,
                        hv[2] + sB[2] + o[2] * d2, hv[3] + sB[3] + o[3] * d2);
    ap[1] = make_float4(hv[4] + sB[4] + o[4] * d2, hv[5] + sB[5] + o[5] * d2,
                        hv[6] + sB[6] + o[6] * d2, hv[7] + sB[7] + o[7] * d2);
}

// ---------------- edge scatter: agg[dst] += dinv[src]*dinv[dst] * hw[src] ----------------
__global__ void __launch_bounds__(256) k_scatter(const int* __restrict__ src,
                                                 const int* __restrict__ dst,
                                                 const float* __restrict__ dinv,
                                                 const float* __restrict__ hw,
                                                 float* __restrict__ agg) {
    int e = blockIdx.x * 256 + threadIdx.x;
    if (e >= NE) return;
    int s = src[e], d = dst[e];
    float nrm = dinv[s] * dinv[d];
    const float4* hp = (const float4*)(hw + (size_t)s * CH);
    float4 a = hp[0], b = hp[1];
    float* ag = agg + (size_t)d * CH;
    atomicAdd(ag + 0, nrm * a.x);
    atomicAdd(ag + 1, nrm * a.y);
    atomicAdd(ag + 2, nrm * a.z);
    atomicAdd(ag + 3, nrm * a.w);
    atomicAdd(ag + 4, nrm * b.x);
    atomicAdd(ag + 5, nrm * b.y);
    atomicAdd(ag + 6, nrm * b.z);
    atomicAdd(ag + 7, nrm * b.w);
}

// ---------------- relu + write h + stats for next conv ----------------
__global__ void k_finish(const float* __restrict__ agg, float* __restrict__ h,
                         double* __restrict__ statsN) {
    int i = blockIdx.x * 256 + threadIdx.x;
    float v[CH];
    if (i < NN) {
        const float4* ap = (const float4*)(agg + (size_t)i * CH);
        float4 a = ap[0], b = ap[1];
        v[0] = fmaxf(a.x, 0.0f); v[1] = fmaxf(a.y, 0.0f);
        v[2] = fmaxf(a.z, 0.0f); v[3] = fmaxf(a.w, 0.0f);
        v[4] = fmaxf(b.x, 0.0f); v[5] = fmaxf(b.y, 0.0f);
        v[6] = fmaxf(b.z, 0.0f); v[7] = fmaxf(b.w, 0.0f);
        float4* hp = (float4*)(h + (size_t)i * CH);
        hp[0] = make_float4(v[0], v[1], v[2], v[3]);
        hp[1] = make_float4(v[4], v[5], v[6], v[7]);
    } else {
#pragma unroll
        for (int c = 0; c < CH; c++) v[c] = 0.0f;
    }
    wave_stats_accum(v, statsN);
}

// ---------------- last conv: relu + pool by graph ----------------
__global__ void k_finish_pool(const float* __restrict__ agg, const int* __restrict__ batch,
                              float* __restrict__ pooled) {
    int i = blockIdx.x * 256 + threadIdx.x;
    if (i >= NN) return;
    const float4* ap = (const float4*)(agg + (size_t)i * CH);
    float4 a = ap[0], b = ap[1];
    float* pp = pooled + (size_t)batch[i] * CH;
    atomicAdd(pp + 0, fmaxf(a.x, 0.0f));
    atomicAdd(pp + 1, fmaxf(a.y, 0.0f));
    atomicAdd(pp + 2, fmaxf(a.z, 0.0f));
    atomicAdd(pp + 3, fmaxf(a.w, 0.0f));
    atomicAdd(pp + 4, fmaxf(b.x, 0.0f));
    atomicAdd(pp + 5, fmaxf(b.y, 0.0f));
    atomicAdd(pp + 6, fmaxf(b.z, 0.0f));
    atomicAdd(pp + 7, fmaxf(b.w, 0.0f));
}

// ---------------- per-graph MLP: relu(pooled @ hid_w + hid_b) @ out_w + out_b ----------------
__global__ void k_mlp(const float* __restrict__ pooled, const float* __restrict__ hid_w,
                      const float* __restrict__ hid_b, const float* __restrict__ out_w,
                      const float* __restrict__ out_b, float* __restrict__ out) {
    int g = blockIdx.x;
    int j = threadIdx.x;  // 128 threads
    __shared__ float sp[CH];
    __shared__ float part[2];
    if (j < CH) sp[j] = pooled[(size_t)g * CH + j];
    __syncthreads();
    float acc = hid_b[j];
#pragma unroll
    for (int c = 0; c < CH; c++) acc += sp[c] * hid_w[c * HID + j];
    acc = fmaxf(acc, 0.0f) * out_w[j];
#pragma unroll
    for (int off = 32; off; off >>= 1) acc += __shfl_xor(acc, off);
    if ((j & 63) == 0) part[j >> 6] = acc;
    __syncthreads();
    if (j == 0) out[g] = part[0] + part[1] + out_b[0];
}

extern "C" void kernel_launch(void* const* d_in, const int* in_sizes, int n_in,
                              void* d_out, int out_size, void* d_ws, size_t ws_size,
                              hipStream_t stream) {
    const int* x = (const int*)d_in[0];
    const int* ei = (const int*)d_in[1];
    const int* srcp = ei;             // edge_index[0]
    const int* dstp = ei + NE;        // edge_index[1]
    const int* batch = (const int*)d_in[2];
    const float* emb = (const float*)d_in[3];
    const float* gamma = (const float*)d_in[4];
    const float* beta = (const float*)d_in[5];
    const float* convw = (const float*)d_in[6];
    const float* convb = (const float*)d_in[7];
    const float* hid_w = (const float*)d_in[8];
    const float* hid_b = (const float*)d_in[9];
    const float* out_w = (const float*)d_in[10];
    const float* out_b = (const float*)d_in[11];
    float* out = (float*)d_out;

    char* ws = (char*)d_ws;
    size_t off = 0;
    float* deg_dinv = (float*)(ws + off); off = alignup(off + (size_t)NN * 4, 256);
    float* h        = (float*)(ws + off); off = alignup(off + (size_t)NN * CH * 4, 256);
    float* hw       = (float*)(ws + off); off = alignup(off + (size_t)NN * CH * 4, 256);
    float* agg      = (float*)(ws + off); off = alignup(off + (size_t)NN * CH * 4, 256);
    float* pooled   = (float*)(ws + off); off = alignup(off + (size_t)NG * CH * 4, 256);
    double* stats   = (double*)(ws + off); off += (size_t)(NCONV + 1) * 2 * CH * 8;

    const int B = 256;
    const int gN = (NN + B - 1) / B;
    const int gE = (NE + B - 1) / B;

    k_init<<<gN, B, 0, stream>>>(deg_dinv, pooled, stats);
    k_degree<<<gE, B, 0, stream>>>(dstp, deg_dinv);
    k_embed<<<gN, B, 0, stream>>>(x, emb, h, deg_dinv, stats);
    for (int i = 0; i < NCONV; i++) {
        k_transform<<<gN, B, 0, stream>>>(h, deg_dinv, stats + (size_t)i * 2 * CH,
                                          gamma + i * CH, beta + i * CH,
                                          convw + i * CH * CH, convb + i * CH, hw, agg);
        k_scatter<<<gE, B, 0, stream>>>(srcp, dstp, deg_dinv, hw, agg);
        if (i < NCONV - 1)
            k_finish<<<gN, B, 0, stream>>>(agg, h, stats + (size_t)(i + 1) * 2 * CH);
        else
            k_finish_pool<<<gN, B, 0, stream>>>(agg, batch, pooled);
    }
    k_mlp<<<NG, HID, 0, stream>>>(pooled, hid_w, hid_b, out_w, out_b, out);
}

// Round 2
// 8995.535 us; speedup vs baseline: 3.6109x; 3.6109x over previous
//
#include <hip/hip_runtime.h>

#define NN 500000
#define NE 8000000
#define NG 5000
#define CH 8
#define NCONV 8
#define HID 128
#define BEPS 1e-5f

#define SCAN_ELEMS 1024                      // elems per scan block (256 thr x 4)
#define NB_SCAN ((NN + SCAN_ELEMS - 1) / SCAN_ELEMS)   // 489

static inline size_t alignup(size_t v, size_t a) { return (v + a - 1) / a * a; }

// ---------------- init: zero hist, pooled, stats ----------------
__global__ void k_init(int* __restrict__ hist, float* __restrict__ pooled,
                       double* __restrict__ stats) {
    int i = blockIdx.x * 256 + threadIdx.x;
    if (i < NN) hist[i] = 0;
    if (i < NG * CH) pooled[i] = 0.0f;
    if (i < (NCONV + 1) * 2 * CH) stats[i] = 0.0;
}

// ---------------- in-degree histogram over dst (int atomics) ----------------
__global__ void k_hist(const int* __restrict__ dst, int* __restrict__ hist) {
    int e = blockIdx.x * 256 + threadIdx.x;
    if (e < NE) atomicAdd(&hist[dst[e]], 1);
}

// ---------------- scan phase 1: per-block sums ----------------
__global__ void k_scan1(const int* __restrict__ hist, int* __restrict__ bsum) {
    int b = blockIdx.x, tid = threadIdx.x;
    int base = b * SCAN_ELEMS + tid * 4;
    int s = 0;
#pragma unroll
    for (int k = 0; k < 4; k++) { int i = base + k; if (i < NN) s += hist[i]; }
#pragma unroll
    for (int off = 32; off; off >>= 1) s += __shfl_xor(s, off);
    __shared__ int wsum[4];
    if ((tid & 63) == 0) wsum[tid >> 6] = s;
    __syncthreads();
    if (tid == 0) bsum[b] = wsum[0] + wsum[1] + wsum[2] + wsum[3];
}

// ---------------- scan phase 2: exclusive scan of block sums (1 block) ----------------
__global__ void k_scan2(int* __restrict__ bsum) {
    __shared__ int s[512];
    int tid = threadIdx.x;
    int v = (tid < NB_SCAN) ? bsum[tid] : 0;
    s[tid] = v;
    __syncthreads();
    for (int off = 1; off < 512; off <<= 1) {
        int t = (tid >= off) ? s[tid - off] : 0;
        __syncthreads();
        s[tid] += t;
        __syncthreads();
    }
    if (tid < NB_SCAN) bsum[tid] = s[tid] - v;  // exclusive
}

// ---------------- scan phase 3: rowptr/cursor/dinv ----------------
__global__ void k_scan3(const int* __restrict__ hist, const int* __restrict__ bsum,
                        int* __restrict__ rowptr, int* __restrict__ cursor,
                        float* __restrict__ dinv) {
    int b = blockIdx.x, tid = threadIdx.x;
    int base = b * SCAN_ELEMS + tid * 4;
    int v[4]; int t4 = 0;
#pragma unroll
    for (int k = 0; k < 4; k++) { int i = base + k; v[k] = (i < NN) ? hist[i] : 0; t4 += v[k]; }
    int incl = t4;
#pragma unroll
    for (int off = 1; off < 64; off <<= 1) {
        int t = __shfl_up(incl, off);
        if ((tid & 63) >= off) incl += t;
    }
    __shared__ int wtot[4];
    if ((tid & 63) == 63) wtot[tid >> 6] = incl;
    __syncthreads();
    int woff = 0;
#pragma unroll
    for (int w = 0; w < 4; w++) if (w < (tid >> 6)) woff += wtot[w];
    int excl = incl - t4 + woff + bsum[b];
#pragma unroll
    for (int k = 0; k < 4; k++) {
        int i = base + k;
        if (i < NN) {
            rowptr[i] = excl;
            cursor[i] = excl;
            dinv[i] = rsqrtf((float)(v[k] + 1));  // +1 self-loop
            excl += v[k];
            if (i == NN - 1) rowptr[NN] = excl;
        }
    }
}

// ---------------- fill CSR: csr[pos] = src, pos from per-dst cursor ----------------
__global__ void k_fill(const int* __restrict__ src, const int* __restrict__ dst,
                       int* __restrict__ cursor, int* __restrict__ csr) {
    int e = blockIdx.x * 256 + threadIdx.x;
    if (e >= NE) return;
    int d = dst[e];
    int pos = atomicAdd(&cursor[d], 1);
    csr[pos] = src[e];
}

// per-wave sum/sumsq reduce of v[CH], lane0 -> f64 atomics into slot[0..7]=sum, [8..15]=sumsq
__device__ __forceinline__ void wave_stats_accum(const float v[CH], double* __restrict__ slot) {
#pragma unroll
    for (int c = 0; c < CH; c++) {
        float s = v[c], q = v[c] * v[c];
#pragma unroll
        for (int off = 32; off; off >>= 1) {
            s += __shfl_xor(s, off);
            q += __shfl_xor(q, off);
        }
        if ((threadIdx.x & 63) == 0) {
            atomicAdd(&slot[c], (double)s);
            atomicAdd(&slot[CH + c], (double)q);
        }
    }
}

// ---------------- embed + stats for conv 0 ----------------
__global__ void k_embed(const int* __restrict__ x, const float* __restrict__ emb,
                        float* __restrict__ h, double* __restrict__ stats0) {
    int i = blockIdx.x * 256 + threadIdx.x;
    float v[CH];
    if (i < NN) {
        int t = x[i];
#pragma unroll
        for (int c = 0; c < CH; c++) v[c] = emb[t * CH + c];
        float4* hp = (float4*)(h + (size_t)i * CH);
        hp[0] = make_float4(v[0], v[1], v[2], v[3]);
        hp[1] = make_float4(v[4], v[5], v[6], v[7]);
    } else {
#pragma unroll
        for (int c = 0; c < CH; c++) v[c] = 0.0f;
    }
    wave_stats_accum(v, stats0);
}

// ---------------- BN + 8x8 linear + agg init (residual + bias + self-loop) ----------------
__global__ void k_transform(const float* __restrict__ h, const float* __restrict__ dinv,
                            const double* __restrict__ stats,
                            const float* __restrict__ gamma, const float* __restrict__ beta,
                            const float* __restrict__ W, const float* __restrict__ bias,
                            float* __restrict__ hw, float* __restrict__ agg) {
    __shared__ float sW[CH * CH], sScale[CH], sShift[CH], sB[CH];
    int tid = threadIdx.x;
    if (tid < CH * CH) sW[tid] = W[tid];
    if (tid < CH) {
        double mu = stats[tid] * (1.0 / NN);
        double var = stats[CH + tid] * (1.0 / NN) - mu * mu;
        float sc = gamma[tid] * rsqrtf((float)var + BEPS);
        sScale[tid] = sc;
        sShift[tid] = beta[tid] - (float)mu * sc;
        sB[tid] = bias[tid];
    }
    __syncthreads();
    int i = blockIdx.x * 256 + tid;
    if (i >= NN) return;
    const float4* hp = (const float4*)(h + (size_t)i * CH);
    float4 h0 = hp[0], h1 = hp[1];
    float hv[CH] = {h0.x, h0.y, h0.z, h0.w, h1.x, h1.y, h1.z, h1.w};
    float hb[CH];
#pragma unroll
    for (int c = 0; c < CH; c++) hb[c] = hv[c] * sScale[c] + sShift[c];
    float o[CH];
#pragma unroll
    for (int j = 0; j < CH; j++) {
        float a = 0.0f;
#pragma unroll
        for (int c = 0; c < CH; c++) a += hb[c] * sW[c * CH + j];
        o[j] = a;
    }
    float d = dinv[i];
    float d2 = d * d;
    float4* hwp = (float4*)(hw + (size_t)i * CH);
    hwp[0] = make_float4(o[0], o[1], o[2], o[3]);
    hwp[1] = make_float4(o[4], o[5], o[6], o[7]);
    float4* ap = (float4*)(agg + (size_t)i * CH);
    ap[0] = make_float4(hv[0] + sB[0] + o[0] * d2, hv[1] + sB[1] + o[1] * d2,
                        hv[2] + sB[2] + o[2] * d2, hv[3] + sB[3] + o[3] * d2);
    ap[1] = make_float4(hv[4] + sB[4] + o[4] * d2, hv[5] + sB[5] + o[5] * d2,
                        hv[6] + sB[6] + o[6] * d2, hv[7] + sB[7] + o[7] * d2);
}

// ---------------- atomic-free gather: agg[n,c] += dinv[n] * sum_e dinv[src]*hw[src,c] ----------------
__global__ void __launch_bounds__(256) k_gather(const int* __restrict__ rowptr,
                                                const int* __restrict__ csr,
                                                const float* __restrict__ dinv,
                                                const float* __restrict__ hw,
                                                float* __restrict__ agg) {
    int t = blockIdx.x * 256 + threadIdx.x;
    int node = t >> 3, c = t & 7;
    if (node >= NN) return;
    int beg = rowptr[node], end = rowptr[node + 1];
    float acc = 0.0f;
    for (int e = beg; e < end; e++) {
        int s = csr[e];                         // broadcast across 8 lanes
        acc += dinv[s] * hw[(size_t)s * CH + c];  // 32B coalesced per edge
    }
    agg[(size_t)node * CH + c] += dinv[node] * acc;
}

// ---------------- relu + write h + stats for next conv ----------------
__global__ void k_finish(const float* __restrict__ agg, float* __restrict__ h,
                         double* __restrict__ statsN) {
    int i = blockIdx.x * 256 + threadIdx.x;
    float v[CH];
    if (i < NN) {
        const float4* ap = (const float4*)(agg + (size_t)i * CH);
        float4 a = ap[0], b = ap[1];
        v[0] = fmaxf(a.x, 0.0f); v[1] = fmaxf(a.y, 0.0f);
        v[2] = fmaxf(a.z, 0.0f); v[3] = fmaxf(a.w, 0.0f);
        v[4] = fmaxf(b.x, 0.0f); v[5] = fmaxf(b.y, 0.0f);
        v[6] = fmaxf(b.z, 0.0f); v[7] = fmaxf(b.w, 0.0f);
        float4* hp = (float4*)(h + (size_t)i * CH);
        hp[0] = make_float4(v[0], v[1], v[2], v[3]);
        hp[1] = make_float4(v[4], v[5], v[6], v[7]);
    } else {
#pragma unroll
        for (int c = 0; c < CH; c++) v[c] = 0.0f;
    }
    wave_stats_accum(v, statsN);
}

// ---------------- last conv: relu + pool by graph ----------------
__global__ void k_finish_pool(const float* __restrict__ agg, const int* __restrict__ batch,
                              float* __restrict__ pooled) {
    int i = blockIdx.x * 256 + threadIdx.x;
    if (i >= NN) return;
    const float4* ap = (const float4*)(agg + (size_t)i * CH);
    float4 a = ap[0], b = ap[1];
    float* pp = pooled + (size_t)batch[i] * CH;
    atomicAdd(pp + 0, fmaxf(a.x, 0.0f));
    atomicAdd(pp + 1, fmaxf(a.y, 0.0f));
    atomicAdd(pp + 2, fmaxf(a.z, 0.0f));
    atomicAdd(pp + 3, fmaxf(a.w, 0.0f));
    atomicAdd(pp + 4, fmaxf(b.x, 0.0f));
    atomicAdd(pp + 5, fmaxf(b.y, 0.0f));
    atomicAdd(pp + 6, fmaxf(b.z, 0.0f));
    atomicAdd(pp + 7, fmaxf(b.w, 0.0f));
}

// ---------------- per-graph MLP ----------------
__global__ void k_mlp(const float* __restrict__ pooled, const float* __restrict__ hid_w,
                      const float* __restrict__ hid_b, const float* __restrict__ out_w,
                      const float* __restrict__ out_b, float* __restrict__ out) {
    int g = blockIdx.x;
    int j = threadIdx.x;  // 128 threads
    __shared__ float sp[CH];
    __shared__ float part[2];
    if (j < CH) sp[j] = pooled[(size_t)g * CH + j];
    __syncthreads();
    float acc = hid_b[j];
#pragma unroll
    for (int c = 0; c < CH; c++) acc += sp[c] * hid_w[c * HID + j];
    acc = fmaxf(acc, 0.0f) * out_w[j];
#pragma unroll
    for (int off = 32; off; off >>= 1) acc += __shfl_xor(acc, off);
    if ((j & 63) == 0) part[j >> 6] = acc;
    __syncthreads();
    if (j == 0) out[g] = part[0] + part[1] + out_b[0];
}

extern "C" void kernel_launch(void* const* d_in, const int* in_sizes, int n_in,
                              void* d_out, int out_size, void* d_ws, size_t ws_size,
                              hipStream_t stream) {
    const int* x = (const int*)d_in[0];
    const int* ei = (const int*)d_in[1];
    const int* srcp = ei;             // edge_index[0]
    const int* dstp = ei + NE;        // edge_index[1]
    const int* batch = (const int*)d_in[2];
    const float* emb = (const float*)d_in[3];
    const float* gamma = (const float*)d_in[4];
    const float* beta = (const float*)d_in[5];
    const float* convw = (const float*)d_in[6];
    const float* convb = (const float*)d_in[7];
    const float* hid_w = (const float*)d_in[8];
    const float* hid_b = (const float*)d_in[9];
    const float* out_w = (const float*)d_in[10];
    const float* out_b = (const float*)d_in[11];
    float* out = (float*)d_out;

    char* ws = (char*)d_ws;
    size_t off = 0;
    int*   hist    = (int*)(ws + off);   off = alignup(off + (size_t)NN * 4, 256);
    int*   cursor  = (int*)(ws + off);   off = alignup(off + (size_t)NN * 4, 256);
    int*   rowptr  = (int*)(ws + off);   off = alignup(off + ((size_t)NN + 1) * 4, 256);
    float* dinv    = (float*)(ws + off); off = alignup(off + (size_t)NN * 4, 256);
    int*   bsum    = (int*)(ws + off);   off = alignup(off + 512 * 4, 256);
    int*   csr     = (int*)(ws + off);   off = alignup(off + (size_t)NE * 4, 256);
    float* h       = (float*)(ws + off); off = alignup(off + (size_t)NN * CH * 4, 256);
    float* hw      = (float*)(ws + off); off = alignup(off + (size_t)NN * CH * 4, 256);
    float* agg     = (float*)(ws + off); off = alignup(off + (size_t)NN * CH * 4, 256);
    float* pooled  = (float*)(ws + off); off = alignup(off + (size_t)NG * CH * 4, 256);
    double* stats  = (double*)(ws + off); off += (size_t)(NCONV + 1) * 2 * CH * 8;

    const int B = 256;
    const int gN = (NN + B - 1) / B;
    const int gE = (NE + B - 1) / B;
    const int gG = (NN * CH + B - 1) / B;

    k_init<<<gN, B, 0, stream>>>(hist, pooled, stats);
    k_hist<<<gE, B, 0, stream>>>(dstp, hist);
    k_scan1<<<NB_SCAN, B, 0, stream>>>(hist, bsum);
    k_scan2<<<1, 512, 0, stream>>>(bsum);
    k_scan3<<<NB_SCAN, B, 0, stream>>>(hist, bsum, rowptr, cursor, dinv);
    k_fill<<<gE, B, 0, stream>>>(srcp, dstp, cursor, csr);
    k_embed<<<gN, B, 0, stream>>>(x, emb, h, stats);
    for (int i = 0; i < NCONV; i++) {
        k_transform<<<gN, B, 0, stream>>>(h, dinv, stats + (size_t)i * 2 * CH,
                                          gamma + i * CH, beta + i * CH,
                                          convw + i * CH * CH, convb + i * CH, hw, agg);
        k_gather<<<gG, B, 0, stream>>>(rowptr, csr, dinv, hw, agg);
        if (i < NCONV - 1)
            k_finish<<<gN, B, 0, stream>>>(agg, h, stats + (size_t)(i + 1) * 2 * CH);
        else
            k_finish_pool<<<gN, B, 0, stream>>>(agg, batch, pooled);
    }
    k_mlp<<<NG, HID, 0, stream>>>(pooled, hid_w, hid_b, out_w, out_b, out);
}

// Round 3
// 3167.606 us; speedup vs baseline: 10.2544x; 2.8399x over previous
//
#include <hip/hip_runtime.h>

#define NN 500000
#define NE 8000000
#define NG 5000
#define CH 8
#define NCONV 8
#define HID 128
#define BEPS 1e-5f

#define NBLK 1954                            // (NN+255)/256
#define SCAN_ELEMS 1024                      // elems per scan block (256 thr x 4)
#define NB_SCAN ((NN + SCAN_ELEMS - 1) / SCAN_ELEMS)   // 489

static inline size_t alignup(size_t v, size_t a) { return (v + a - 1) / a * a; }

// ---------------- init: zero hist + pooled ----------------
__global__ void k_init(int* __restrict__ hist, float* __restrict__ pooled) {
    int i = blockIdx.x * 256 + threadIdx.x;
    if (i < NN) hist[i] = 0;
    if (i < NG * CH) pooled[i] = 0.0f;
}

// ---------------- in-degree histogram over dst (int atomics) ----------------
__global__ void k_hist(const int* __restrict__ dst, int* __restrict__ hist) {
    int e = blockIdx.x * 256 + threadIdx.x;
    if (e < NE) atomicAdd(&hist[dst[e]], 1);
}

// ---------------- scan phase 1: per-block sums ----------------
__global__ void k_scan1(const int* __restrict__ hist, int* __restrict__ bsum) {
    int b = blockIdx.x, tid = threadIdx.x;
    int base = b * SCAN_ELEMS + tid * 4;
    int s = 0;
#pragma unroll
    for (int k = 0; k < 4; k++) { int i = base + k; if (i < NN) s += hist[i]; }
#pragma unroll
    for (int off = 32; off; off >>= 1) s += __shfl_xor(s, off);
    __shared__ int wsum[4];
    if ((tid & 63) == 0) wsum[tid >> 6] = s;
    __syncthreads();
    if (tid == 0) bsum[b] = wsum[0] + wsum[1] + wsum[2] + wsum[3];
}

// ---------------- scan phase 2: exclusive scan of block sums (1 block) ----------------
__global__ void k_scan2(int* __restrict__ bsum) {
    __shared__ int s[512];
    int tid = threadIdx.x;
    int v = (tid < NB_SCAN) ? bsum[tid] : 0;
    s[tid] = v;
    __syncthreads();
    for (int off = 1; off < 512; off <<= 1) {
        int t = (tid >= off) ? s[tid - off] : 0;
        __syncthreads();
        s[tid] += t;
        __syncthreads();
    }
    if (tid < NB_SCAN) bsum[tid] = s[tid] - v;  // exclusive
}

// ---------------- scan phase 3: rowptr/cursor/dinv ----------------
__global__ void k_scan3(const int* __restrict__ hist, const int* __restrict__ bsum,
                        int* __restrict__ rowptr, int* __restrict__ cursor,
                        float* __restrict__ dinv) {
    int b = blockIdx.x, tid = threadIdx.x;
    int base = b * SCAN_ELEMS + tid * 4;
    int v[4]; int t4 = 0;
#pragma unroll
    for (int k = 0; k < 4; k++) { int i = base + k; v[k] = (i < NN) ? hist[i] : 0; t4 += v[k]; }
    int incl = t4;
#pragma unroll
    for (int off = 1; off < 64; off <<= 1) {
        int t = __shfl_up(incl, off);
        if ((tid & 63) >= off) incl += t;
    }
    __shared__ int wtot[4];
    if ((tid & 63) == 63) wtot[tid >> 6] = incl;
    __syncthreads();
    int woff = 0;
#pragma unroll
    for (int w = 0; w < 4; w++) if (w < (tid >> 6)) woff += wtot[w];
    int excl = incl - t4 + woff + bsum[b];
#pragma unroll
    for (int k = 0; k < 4; k++) {
        int i = base + k;
        if (i < NN) {
            rowptr[i] = excl;
            cursor[i] = excl;
            dinv[i] = rsqrtf((float)(v[k] + 1));  // +1 self-loop
            excl += v[k];
            if (i == NN - 1) rowptr[NN] = excl;
        }
    }
}

// ---------------- fill CSR: csr[pos] = src, pos from per-dst cursor ----------------
__global__ void k_fill(const int* __restrict__ src, const int* __restrict__ dst,
                       int* __restrict__ cursor, int* __restrict__ csr) {
    int e = blockIdx.x * 256 + threadIdx.x;
    if (e >= NE) return;
    int d = dst[e];
    int pos = atomicAdd(&cursor[d], 1);
    csr[pos] = src[e];
}

// block-level sum/sumsq of v[CH] -> partial[blockIdx*16 + (0..7 sum, 8..15 sumsq)], NO atomics
__device__ __forceinline__ void block_stats_accum(const float v[CH], float* __restrict__ partial) {
    __shared__ float ls[4][2 * CH];
    int tid = threadIdx.x;
#pragma unroll
    for (int c = 0; c < CH; c++) {
        float s = v[c], q = v[c] * v[c];
#pragma unroll
        for (int off = 32; off; off >>= 1) {
            s += __shfl_xor(s, off);
            q += __shfl_xor(q, off);
        }
        if ((tid & 63) == 0) {
            ls[tid >> 6][c] = s;
            ls[tid >> 6][CH + c] = q;
        }
    }
    __syncthreads();
    if (tid < 2 * CH)
        partial[(size_t)blockIdx.x * 2 * CH + tid] =
            ls[0][tid] + ls[1][tid] + ls[2][tid] + ls[3][tid];
}

// ---------------- reduce partials -> stats[16] (f64) ----------------
__global__ void k_rstats(const float* __restrict__ partial, double* __restrict__ stats) {
    int tid = threadIdx.x;
    int slot = tid & 15;
    double acc = 0.0;
    for (int j = tid >> 4; j < NBLK; j += 16) acc += (double)partial[j * 16 + slot];
    acc += __shfl_xor(acc, 16);
    acc += __shfl_xor(acc, 32);
    __shared__ double ls[4][16];
    if ((tid & 63) < 16) ls[tid >> 6][slot] = acc;
    __syncthreads();
    if (tid < 16) stats[tid] = ls[0][tid] + ls[1][tid] + ls[2][tid] + ls[3][tid];
}

// ---------------- embed + block stats ----------------
__global__ void k_embed(const int* __restrict__ x, const float* __restrict__ emb,
                        float* __restrict__ h, float* __restrict__ partial) {
    int i = blockIdx.x * 256 + threadIdx.x;
    float v[CH];
    if (i < NN) {
        int t = x[i];
#pragma unroll
        for (int c = 0; c < CH; c++) v[c] = emb[t * CH + c];
        float4* hp = (float4*)(h + (size_t)i * CH);
        hp[0] = make_float4(v[0], v[1], v[2], v[3]);
        hp[1] = make_float4(v[4], v[5], v[6], v[7]);
    } else {
#pragma unroll
        for (int c = 0; c < CH; c++) v[c] = 0.0f;
    }
    block_stats_accum(v, partial);
}

// ---------------- BN + 8x8 linear + agg init (residual + bias + self-loop) ----------------
__global__ void k_transform(const float* __restrict__ h, const float* __restrict__ dinv,
                            const double* __restrict__ stats,
                            const float* __restrict__ gamma, const float* __restrict__ beta,
                            const float* __restrict__ W, const float* __restrict__ bias,
                            float* __restrict__ hw, float* __restrict__ agg) {
    __shared__ float sW[CH * CH], sScale[CH], sShift[CH], sB[CH];
    int tid = threadIdx.x;
    if (tid < CH * CH) sW[tid] = W[tid];
    if (tid < CH) {
        double mu = stats[tid] * (1.0 / NN);
        double var = stats[CH + tid] * (1.0 / NN) - mu * mu;
        float sc = gamma[tid] * rsqrtf((float)var + BEPS);
        sScale[tid] = sc;
        sShift[tid] = beta[tid] - (float)mu * sc;
        sB[tid] = bias[tid];
    }
    __syncthreads();
    int i = blockIdx.x * 256 + tid;
    if (i >= NN) return;
    const float4* hp = (const float4*)(h + (size_t)i * CH);
    float4 h0 = hp[0], h1 = hp[1];
    float hv[CH] = {h0.x, h0.y, h0.z, h0.w, h1.x, h1.y, h1.z, h1.w};
    float hb[CH];
#pragma unroll
    for (int c = 0; c < CH; c++) hb[c] = hv[c] * sScale[c] + sShift[c];
    float o[CH];
#pragma unroll
    for (int j = 0; j < CH; j++) {
        float a = 0.0f;
#pragma unroll
        for (int c = 0; c < CH; c++) a += hb[c] * sW[c * CH + j];
        o[j] = a;
    }
    float d = dinv[i];
    float d2 = d * d;
    float4* hwp = (float4*)(hw + (size_t)i * CH);
    hwp[0] = make_float4(o[0], o[1], o[2], o[3]);
    hwp[1] = make_float4(o[4], o[5], o[6], o[7]);
    float4* ap = (float4*)(agg + (size_t)i * CH);
    ap[0] = make_float4(hv[0] + sB[0] + o[0] * d2, hv[1] + sB[1] + o[1] * d2,
                        hv[2] + sB[2] + o[2] * d2, hv[3] + sB[3] + o[3] * d2);
    ap[1] = make_float4(hv[4] + sB[4] + o[4] * d2, hv[5] + sB[5] + o[5] * d2,
                        hv[6] + sB[6] + o[6] * d2, hv[7] + sB[7] + o[7] * d2);
}

// ---------------- atomic-free gather: agg[n,c] += dinv[n] * sum_e dinv[src]*hw[src,c] ----------------
__global__ void __launch_bounds__(256) k_gather(const int* __restrict__ rowptr,
                                                const int* __restrict__ csr,
                                                const float* __restrict__ dinv,
                                                const float* __restrict__ hw,
                                                float* __restrict__ agg) {
    int t = blockIdx.x * 256 + threadIdx.x;
    int node = t >> 3, c = t & 7;
    if (node >= NN) return;
    int beg = rowptr[node], end = rowptr[node + 1];
    float acc = 0.0f;
    for (int e = beg; e < end; e++) {
        int s = csr[e];                           // broadcast across 8 lanes
        acc += dinv[s] * hw[(size_t)s * CH + c];  // 32B coalesced per edge
    }
    agg[(size_t)node * CH + c] += dinv[node] * acc;
}

// ---------------- relu + write h + block stats ----------------
__global__ void k_finish(const float* __restrict__ agg, float* __restrict__ h,
                         float* __restrict__ partial) {
    int i = blockIdx.x * 256 + threadIdx.x;
    float v[CH];
    if (i < NN) {
        const float4* ap = (const float4*)(agg + (size_t)i * CH);
        float4 a = ap[0], b = ap[1];
        v[0] = fmaxf(a.x, 0.0f); v[1] = fmaxf(a.y, 0.0f);
        v[2] = fmaxf(a.z, 0.0f); v[3] = fmaxf(a.w, 0.0f);
        v[4] = fmaxf(b.x, 0.0f); v[5] = fmaxf(b.y, 0.0f);
        v[6] = fmaxf(b.z, 0.0f); v[7] = fmaxf(b.w, 0.0f);
        float4* hp = (float4*)(h + (size_t)i * CH);
        hp[0] = make_float4(v[0], v[1], v[2], v[3]);
        hp[1] = make_float4(v[4], v[5], v[6], v[7]);
    } else {
#pragma unroll
        for (int c = 0; c < CH; c++) v[c] = 0.0f;
    }
    block_stats_accum(v, partial);
}

// ---------------- last conv: relu + pool by graph ----------------
__global__ void k_finish_pool(const float* __restrict__ agg, const int* __restrict__ batch,
                              float* __restrict__ pooled) {
    int i = blockIdx.x * 256 + threadIdx.x;
    if (i >= NN) return;
    const float4* ap = (const float4*)(agg + (size_t)i * CH);
    float4 a = ap[0], b = ap[1];
    float* pp = pooled + (size_t)batch[i] * CH;
    atomicAdd(pp + 0, fmaxf(a.x, 0.0f));
    atomicAdd(pp + 1, fmaxf(a.y, 0.0f));
    atomicAdd(pp + 2, fmaxf(a.z, 0.0f));
    atomicAdd(pp + 3, fmaxf(a.w, 0.0f));
    atomicAdd(pp + 4, fmaxf(b.x, 0.0f));
    atomicAdd(pp + 5, fmaxf(b.y, 0.0f));
    atomicAdd(pp + 6, fmaxf(b.z, 0.0f));
    atomicAdd(pp + 7, fmaxf(b.w, 0.0f));
}

// ---------------- per-graph MLP ----------------
__global__ void k_mlp(const float* __restrict__ pooled, const float* __restrict__ hid_w,
                      const float* __restrict__ hid_b, const float* __restrict__ out_w,
                      const float* __restrict__ out_b, float* __restrict__ out) {
    int g = blockIdx.x;
    int j = threadIdx.x;  // 128 threads
    __shared__ float sp[CH];
    __shared__ float part[2];
    if (j < CH) sp[j] = pooled[(size_t)g * CH + j];
    __syncthreads();
    float acc = hid_b[j];
#pragma unroll
    for (int c = 0; c < CH; c++) acc += sp[c] * hid_w[c * HID + j];
    acc = fmaxf(acc, 0.0f) * out_w[j];
#pragma unroll
    for (int off = 32; off; off >>= 1) acc += __shfl_xor(acc, off);
    if ((j & 63) == 0) part[j >> 6] = acc;
    __syncthreads();
    if (j == 0) out[g] = part[0] + part[1] + out_b[0];
}

extern "C" void kernel_launch(void* const* d_in, const int* in_sizes, int n_in,
                              void* d_out, int out_size, void* d_ws, size_t ws_size,
                              hipStream_t stream) {
    const int* x = (const int*)d_in[0];
    const int* ei = (const int*)d_in[1];
    const int* srcp = ei;             // edge_index[0]
    const int* dstp = ei + NE;        // edge_index[1]
    const int* batch = (const int*)d_in[2];
    const float* emb = (const float*)d_in[3];
    const float* gamma = (const float*)d_in[4];
    const float* beta = (const float*)d_in[5];
    const float* convw = (const float*)d_in[6];
    const float* convb = (const float*)d_in[7];
    const float* hid_w = (const float*)d_in[8];
    const float* hid_b = (const float*)d_in[9];
    const float* out_w = (const float*)d_in[10];
    const float* out_b = (const float*)d_in[11];
    float* out = (float*)d_out;

    char* ws = (char*)d_ws;
    size_t off = 0;
    int*   hist    = (int*)(ws + off);   off = alignup(off + (size_t)NN * 4, 256);
    int*   cursor  = (int*)(ws + off);   off = alignup(off + (size_t)NN * 4, 256);
    int*   rowptr  = (int*)(ws + off);   off = alignup(off + ((size_t)NN + 1) * 4, 256);
    float* dinv    = (float*)(ws + off); off = alignup(off + (size_t)NN * 4, 256);
    int*   bsum    = (int*)(ws + off);   off = alignup(off + 512 * 4, 256);
    int*   csr     = (int*)(ws + off);   off = alignup(off + (size_t)NE * 4, 256);
    float* h       = (float*)(ws + off); off = alignup(off + (size_t)NN * CH * 4, 256);
    float* hw      = (float*)(ws + off); off = alignup(off + (size_t)NN * CH * 4, 256);
    float* agg     = (float*)(ws + off); off = alignup(off + (size_t)NN * CH * 4, 256);
    float* pooled  = (float*)(ws + off); off = alignup(off + (size_t)NG * CH * 4, 256);
    float* partial = (float*)(ws + off); off = alignup(off + (size_t)NBLK * 2 * CH * 4, 256);
    double* stats  = (double*)(ws + off); off += 2 * CH * 8;

    const int B = 256;
    const int gN = NBLK;
    const int gE = (NE + B - 1) / B;
    const int gG = (NN * CH + B - 1) / B;

    k_init<<<gN, B, 0, stream>>>(hist, pooled);
    k_hist<<<gE, B, 0, stream>>>(dstp, hist);
    k_scan1<<<NB_SCAN, B, 0, stream>>>(hist, bsum);
    k_scan2<<<1, 512, 0, stream>>>(bsum);
    k_scan3<<<NB_SCAN, B, 0, stream>>>(hist, bsum, rowptr, cursor, dinv);
    k_fill<<<gE, B, 0, stream>>>(srcp, dstp, cursor, csr);
    k_embed<<<gN, B, 0, stream>>>(x, emb, h, partial);
    k_rstats<<<1, 256, 0, stream>>>(partial, stats);
    for (int i = 0; i < NCONV; i++) {
        k_transform<<<gN, B, 0, stream>>>(h, dinv, stats,
                                          gamma + i * CH, beta + i * CH,
                                          convw + i * CH * CH, convb + i * CH, hw, agg);
        k_gather<<<gG, B, 0, stream>>>(rowptr, csr, dinv, hw, agg);
        if (i < NCONV - 1) {
            k_finish<<<gN, B, 0, stream>>>(agg, h, partial);
            k_rstats<<<1, 256, 0, stream>>>(partial, stats);
        } else {
            k_finish_pool<<<gN, B, 0, stream>>>(agg, batch, pooled);
        }
    }
    k_mlp<<<NG, HID, 0, stream>>>(pooled, hid_w, hid_b, out_w, out_b, out);
}

// Round 4
// 2392.410 us; speedup vs baseline: 13.5770x; 1.3240x over previous
//
#include <hip/hip_runtime.h>

#define NN 500000
#define NE 8000000
#define NG 5000
#define CH 8
#define NCONV 8
#define HID 128
#define BEPS 1e-5f

#define NBLK 1954                            // (NN+255)/256
#define SCAN_ELEMS 1024                      // elems per scan block (256 thr x 4)
#define NB_SCAN ((NN + SCAN_ELEMS - 1) / SCAN_ELEMS)   // 489

#define NWIN 8                               // dst windows (one per XCD)
#define WIN (NN / NWIN)                      // 62500 nodes per window
#define FCHUNK 8192                          // edges per block-chunk in windowed passes
#define NCHUNK ((NE + FCHUNK - 1) / FCHUNK)  // 977

static inline size_t alignup(size_t v, size_t a) { return (v + a - 1) / a * a; }

// ---------------- init: zero hist + pooled ----------------
__global__ void k_init(int* __restrict__ hist, float* __restrict__ pooled) {
    int i = blockIdx.x * 256 + threadIdx.x;
    if (i < NN) hist[i] = 0;
    if (i < NG * CH) pooled[i] = 0.0f;
}

// ---------------- windowed in-degree histogram: block b -> window b&7, chunk b>>3 ----------------
__global__ void k_hist(const int* __restrict__ dst, int* __restrict__ hist) {
    int w = blockIdx.x & (NWIN - 1);
    int chunk = blockIdx.x >> 3;
    int lo = w * WIN, hi = lo + WIN;
    int base = chunk * FCHUNK + threadIdx.x;
#pragma unroll
    for (int k = 0; k < FCHUNK / 256; k++) {
        int e = base + k * 256;
        if (e < NE) {
            int d = dst[e];
            if (d >= lo && d < hi) atomicAdd(&hist[d], 1);
        }
    }
}

// ---------------- scan phase 1: per-block sums ----------------
__global__ void k_scan1(const int* __restrict__ hist, int* __restrict__ bsum) {
    int b = blockIdx.x, tid = threadIdx.x;
    int base = b * SCAN_ELEMS + tid * 4;
    int s = 0;
#pragma unroll
    for (int k = 0; k < 4; k++) { int i = base + k; if (i < NN) s += hist[i]; }
#pragma unroll
    for (int off = 32; off; off >>= 1) s += __shfl_xor(s, off);
    __shared__ int wsum[4];
    if ((tid & 63) == 0) wsum[tid >> 6] = s;
    __syncthreads();
    if (tid == 0) bsum[b] = wsum[0] + wsum[1] + wsum[2] + wsum[3];
}

// ---------------- scan phase 2: exclusive scan of block sums (1 block) ----------------
__global__ void k_scan2(int* __restrict__ bsum) {
    __shared__ int s[512];
    int tid = threadIdx.x;
    int v = (tid < NB_SCAN) ? bsum[tid] : 0;
    s[tid] = v;
    __syncthreads();
    for (int off = 1; off < 512; off <<= 1) {
        int t = (tid >= off) ? s[tid - off] : 0;
        __syncthreads();
        s[tid] += t;
        __syncthreads();
    }
    if (tid < NB_SCAN) bsum[tid] = s[tid] - v;  // exclusive
}

// ---------------- scan phase 3: rowptr/cursor/dinv ----------------
__global__ void k_scan3(const int* __restrict__ hist, const int* __restrict__ bsum,
                        int* __restrict__ rowptr, int* __restrict__ cursor,
                        float* __restrict__ dinv) {
    int b = blockIdx.x, tid = threadIdx.x;
    int base = b * SCAN_ELEMS + tid * 4;
    int v[4]; int t4 = 0;
#pragma unroll
    for (int k = 0; k < 4; k++) { int i = base + k; v[k] = (i < NN) ? hist[i] : 0; t4 += v[k]; }
    int incl = t4;
#pragma unroll
    for (int off = 1; off < 64; off <<= 1) {
        int t = __shfl_up(incl, off);
        if ((tid & 63) >= off) incl += t;
    }
    __shared__ int wtot[4];
    if ((tid & 63) == 63) wtot[tid >> 6] = incl;
    __syncthreads();
    int woff = 0;
#pragma unroll
    for (int w = 0; w < 4; w++) if (w < (tid >> 6)) woff += wtot[w];
    int excl = incl - t4 + woff + bsum[b];
#pragma unroll
    for (int k = 0; k < 4; k++) {
        int i = base + k;
        if (i < NN) {
            rowptr[i] = excl;
            cursor[i] = excl;
            dinv[i] = rsqrtf((float)(v[k] + 1));  // +1 self-loop
            excl += v[k];
            if (i == NN - 1) rowptr[NN] = excl;
        }
    }
}

// ---------------- windowed CSR fill: csr writes stay in one XCD's L2 window ----------------
__global__ void k_fill(const int* __restrict__ src, const int* __restrict__ dst,
                       int* __restrict__ cursor, int* __restrict__ csr) {
    int w = blockIdx.x & (NWIN - 1);
    int chunk = blockIdx.x >> 3;
    int lo = w * WIN, hi = lo + WIN;
    int base = chunk * FCHUNK + threadIdx.x;
#pragma unroll
    for (int k = 0; k < FCHUNK / 256; k++) {
        int e = base + k * 256;
        if (e < NE) {
            int d = dst[e];
            if (d >= lo && d < hi) {
                int pos = atomicAdd(&cursor[d], 1);
                csr[pos] = src[e];
            }
        }
    }
}

// block-level sum/sumsq of v[CH] -> partial[blockIdx*16 + (0..7 sum, 8..15 sumsq)], NO atomics
__device__ __forceinline__ void block_stats_accum(const float v[CH], float* __restrict__ partial) {
    __shared__ float ls[4][2 * CH];
    int tid = threadIdx.x;
#pragma unroll
    for (int c = 0; c < CH; c++) {
        float s = v[c], q = v[c] * v[c];
#pragma unroll
        for (int off = 32; off; off >>= 1) {
            s += __shfl_xor(s, off);
            q += __shfl_xor(q, off);
        }
        if ((tid & 63) == 0) {
            ls[tid >> 6][c] = s;
            ls[tid >> 6][CH + c] = q;
        }
    }
    __syncthreads();
    if (tid < 2 * CH)
        partial[(size_t)blockIdx.x * 2 * CH + tid] =
            ls[0][tid] + ls[1][tid] + ls[2][tid] + ls[3][tid];
}

// ---------------- reduce partials -> stats[16] (f64) ----------------
__global__ void k_rstats(const float* __restrict__ partial, double* __restrict__ stats) {
    int tid = threadIdx.x;
    int slot = tid & 15;
    double acc = 0.0;
    for (int j = tid >> 4; j < NBLK; j += 16) acc += (double)partial[j * 16 + slot];
    acc += __shfl_xor(acc, 16);
    acc += __shfl_xor(acc, 32);
    __shared__ double ls[4][16];
    if ((tid & 63) < 16) ls[tid >> 6][slot] = acc;
    __syncthreads();
    if (tid < 16) stats[tid] = ls[0][tid] + ls[1][tid] + ls[2][tid] + ls[3][tid];
}

// ---------------- embed + block stats ----------------
__global__ void k_embed(const int* __restrict__ x, const float* __restrict__ emb,
                        float* __restrict__ h, float* __restrict__ partial) {
    int i = blockIdx.x * 256 + threadIdx.x;
    float v[CH];
    if (i < NN) {
        int t = x[i];
#pragma unroll
        for (int c = 0; c < CH; c++) v[c] = emb[t * CH + c];
        float4* hp = (float4*)(h + (size_t)i * CH);
        hp[0] = make_float4(v[0], v[1], v[2], v[3]);
        hp[1] = make_float4(v[4], v[5], v[6], v[7]);
    } else {
#pragma unroll
        for (int c = 0; c < CH; c++) v[c] = 0.0f;
    }
    block_stats_accum(v, partial);
}

// ---------------- BN + 8x8 linear + agg init; writes hws = dinv[i]*o (pre-scaled message) ----------------
__global__ void k_transform(const float* __restrict__ h, const float* __restrict__ dinv,
                            const double* __restrict__ stats,
                            const float* __restrict__ gamma, const float* __restrict__ beta,
                            const float* __restrict__ W, const float* __restrict__ bias,
                            float* __restrict__ hws, float* __restrict__ agg) {
    __shared__ float sW[CH * CH], sScale[CH], sShift[CH], sB[CH];
    int tid = threadIdx.x;
    if (tid < CH * CH) sW[tid] = W[tid];
    if (tid < CH) {
        double mu = stats[tid] * (1.0 / NN);
        double var = stats[CH + tid] * (1.0 / NN) - mu * mu;
        float sc = gamma[tid] * rsqrtf((float)var + BEPS);
        sScale[tid] = sc;
        sShift[tid] = beta[tid] - (float)mu * sc;
        sB[tid] = bias[tid];
    }
    __syncthreads();
    int i = blockIdx.x * 256 + tid;
    if (i >= NN) return;
    const float4* hp = (const float4*)(h + (size_t)i * CH);
    float4 h0 = hp[0], h1 = hp[1];
    float hv[CH] = {h0.x, h0.y, h0.z, h0.w, h1.x, h1.y, h1.z, h1.w};
    float hb[CH];
#pragma unroll
    for (int c = 0; c < CH; c++) hb[c] = hv[c] * sScale[c] + sShift[c];
    float o[CH];
#pragma unroll
    for (int j = 0; j < CH; j++) {
        float a = 0.0f;
#pragma unroll
        for (int c = 0; c < CH; c++) a += hb[c] * sW[c * CH + j];
        o[j] = a;
    }
    float d = dinv[i];
    float d2 = d * d;
    float4* hwp = (float4*)(hws + (size_t)i * CH);
    hwp[0] = make_float4(o[0] * d, o[1] * d, o[2] * d, o[3] * d);
    hwp[1] = make_float4(o[4] * d, o[5] * d, o[6] * d, o[7] * d);
    float4* ap = (float4*)(agg + (size_t)i * CH);
    ap[0] = make_float4(hv[0] + sB[0] + o[0] * d2, hv[1] + sB[1] + o[1] * d2,
                        hv[2] + sB[2] + o[2] * d2, hv[3] + sB[3] + o[3] * d2);
    ap[1] = make_float4(hv[4] + sB[4] + o[4] * d2, hv[5] + sB[5] + o[5] * d2,
                        hv[6] + sB[6] + o[6] * d2, hv[7] + sB[7] + o[7] * d2);
}

// ---------------- atomic-free gather: agg[n,c] += dinv[n] * sum_e hws[src,c] ----------------
__global__ void __launch_bounds__(256) k_gather(const int* __restrict__ rowptr,
                                                const int* __restrict__ csr,
                                                const float* __restrict__ dinv,
                                                const float* __restrict__ hws,
                                                float* __restrict__ agg) {
    int t = blockIdx.x * 256 + threadIdx.x;
    int node = t >> 3, c = t & 7;
    if (node >= NN) return;
    int beg = rowptr[node], end = rowptr[node + 1];
    float acc = 0.0f;
    int e = beg;
    for (; e + 1 < end; e += 2) {
        int s0 = csr[e], s1 = csr[e + 1];
        acc += hws[(size_t)s0 * CH + c] + hws[(size_t)s1 * CH + c];
    }
    if (e < end) acc += hws[(size_t)csr[e] * CH + c];
    agg[(size_t)node * CH + c] += dinv[node] * acc;
}

// ---------------- relu + write h + block stats ----------------
__global__ void k_finish(const float* __restrict__ agg, float* __restrict__ h,
                         float* __restrict__ partial) {
    int i = blockIdx.x * 256 + threadIdx.x;
    float v[CH];
    if (i < NN) {
        const float4* ap = (const float4*)(agg + (size_t)i * CH);
        float4 a = ap[0], b = ap[1];
        v[0] = fmaxf(a.x, 0.0f); v[1] = fmaxf(a.y, 0.0f);
        v[2] = fmaxf(a.z, 0.0f); v[3] = fmaxf(a.w, 0.0f);
        v[4] = fmaxf(b.x, 0.0f); v[5] = fmaxf(b.y, 0.0f);
        v[6] = fmaxf(b.z, 0.0f); v[7] = fmaxf(b.w, 0.0f);
        float4* hp = (float4*)(h + (size_t)i * CH);
        hp[0] = make_float4(v[0], v[1], v[2], v[3]);
        hp[1] = make_float4(v[4], v[5], v[6], v[7]);
    } else {
#pragma unroll
        for (int c = 0; c < CH; c++) v[c] = 0.0f;
    }
    block_stats_accum(v, partial);
}

// ---------------- last conv: relu + pool by graph ----------------
__global__ void k_finish_pool(const float* __restrict__ agg, const int* __restrict__ batch,
                              float* __restrict__ pooled) {
    int i = blockIdx.x * 256 + threadIdx.x;
    if (i >= NN) return;
    const float4* ap = (const float4*)(agg + (size_t)i * CH);
    float4 a = ap[0], b = ap[1];
    float* pp = pooled + (size_t)batch[i] * CH;
    atomicAdd(pp + 0, fmaxf(a.x, 0.0f));
    atomicAdd(pp + 1, fmaxf(a.y, 0.0f));
    atomicAdd(pp + 2, fmaxf(a.z, 0.0f));
    atomicAdd(pp + 3, fmaxf(a.w, 0.0f));
    atomicAdd(pp + 4, fmaxf(b.x, 0.0f));
    atomicAdd(pp + 5, fmaxf(b.y, 0.0f));
    atomicAdd(pp + 6, fmaxf(b.z, 0.0f));
    atomicAdd(pp + 7, fmaxf(b.w, 0.0f));
}

// ---------------- per-graph MLP ----------------
__global__ void k_mlp(const float* __restrict__ pooled, const float* __restrict__ hid_w,
                      const float* __restrict__ hid_b, const float* __restrict__ out_w,
                      const float* __restrict__ out_b, float* __restrict__ out) {
    int g = blockIdx.x;
    int j = threadIdx.x;  // 128 threads
    __shared__ float sp[CH];
    __shared__ float part[2];
    if (j < CH) sp[j] = pooled[(size_t)g * CH + j];
    __syncthreads();
    float acc = hid_b[j];
#pragma unroll
    for (int c = 0; c < CH; c++) acc += sp[c] * hid_w[c * HID + j];
    acc = fmaxf(acc, 0.0f) * out_w[j];
#pragma unroll
    for (int off = 32; off; off >>= 1) acc += __shfl_xor(acc, off);
    if ((j & 63) == 0) part[j >> 6] = acc;
    __syncthreads();
    if (j == 0) out[g] = part[0] + part[1] + out_b[0];
}

extern "C" void kernel_launch(void* const* d_in, const int* in_sizes, int n_in,
                              void* d_out, int out_size, void* d_ws, size_t ws_size,
                              hipStream_t stream) {
    const int* x = (const int*)d_in[0];
    const int* ei = (const int*)d_in[1];
    const int* srcp = ei;             // edge_index[0]
    const int* dstp = ei + NE;        // edge_index[1]
    const int* batch = (const int*)d_in[2];
    const float* emb = (const float*)d_in[3];
    const float* gamma = (const float*)d_in[4];
    const float* beta = (const float*)d_in[5];
    const float* convw = (const float*)d_in[6];
    const float* convb = (const float*)d_in[7];
    const float* hid_w = (const float*)d_in[8];
    const float* hid_b = (const float*)d_in[9];
    const float* out_w = (const float*)d_in[10];
    const float* out_b = (const float*)d_in[11];
    float* out = (float*)d_out;

    char* ws = (char*)d_ws;
    size_t off = 0;
    int*   hist    = (int*)(ws + off);   off = alignup(off + (size_t)NN * 4, 256);
    int*   cursor  = (int*)(ws + off);   off = alignup(off + (size_t)NN * 4, 256);
    int*   rowptr  = (int*)(ws + off);   off = alignup(off + ((size_t)NN + 1) * 4, 256);
    float* dinv    = (float*)(ws + off); off = alignup(off + (size_t)NN * 4, 256);
    int*   bsum    = (int*)(ws + off);   off = alignup(off + 512 * 4, 256);
    int*   csr     = (int*)(ws + off);   off = alignup(off + (size_t)NE * 4, 256);
    float* h       = (float*)(ws + off); off = alignup(off + (size_t)NN * CH * 4, 256);
    float* hws     = (float*)(ws + off); off = alignup(off + (size_t)NN * CH * 4, 256);
    float* agg     = (float*)(ws + off); off = alignup(off + (size_t)NN * CH * 4, 256);
    float* pooled  = (float*)(ws + off); off = alignup(off + (size_t)NG * CH * 4, 256);
    float* partial = (float*)(ws + off); off = alignup(off + (size_t)NBLK * 2 * CH * 4, 256);
    double* stats  = (double*)(ws + off); off += 2 * CH * 8;

    const int B = 256;
    const int gN = NBLK;
    const int gW = NCHUNK * NWIN;   // windowed edge passes
    const int gG = (NN * CH + B - 1) / B;

    k_init<<<gN, B, 0, stream>>>(hist, pooled);
    k_hist<<<gW, B, 0, stream>>>(dstp, hist);
    k_scan1<<<NB_SCAN, B, 0, stream>>>(hist, bsum);
    k_scan2<<<1, 512, 0, stream>>>(bsum);
    k_scan3<<<NB_SCAN, B, 0, stream>>>(hist, bsum, rowptr, cursor, dinv);
    k_fill<<<gW, B, 0, stream>>>(srcp, dstp, cursor, csr);
    k_embed<<<gN, B, 0, stream>>>(x, emb, h, partial);
    k_rstats<<<1, 256, 0, stream>>>(partial, stats);
    for (int i = 0; i < NCONV; i++) {
        k_transform<<<gN, B, 0, stream>>>(h, dinv, stats,
                                          gamma + i * CH, beta + i * CH,
                                          convw + i * CH * CH, convb + i * CH, hws, agg);
        k_gather<<<gG, B, 0, stream>>>(rowptr, csr, dinv, hws, agg);
        if (i < NCONV - 1) {
            k_finish<<<gN, B, 0, stream>>>(agg, h, partial);
            k_rstats<<<1, 256, 0, stream>>>(partial, stats);
        } else {
            k_finish_pool<<<gN, B, 0, stream>>>(agg, batch, pooled);
        }
    }
    k_mlp<<<NG, HID, 0, stream>>>(pooled, hid_w, hid_b, out_w, out_b, out);
}